// Round 1
// baseline (242.328 us; speedup 1.0000x reference)
//
#include <hip/hip_runtime.h>

// Problem: B=64, S=512, D=768 fp32.
// out = concat( hidden[:,0,:]  (B*D floats),
//               segment-mean over S by sent_id (B*20*768 floats) )
// sent_ids in [0,20]; segment 20 accumulated but dropped.

constexpr int B_ = 64;
constexpr int S_ = 512;
constexpr int D_ = 768;
constexpr int M1 = 21;     // max_sents + 1 segments accumulated
constexpr int MS = 20;     // segments emitted
constexpr int CHUNK = 192; // D / 4 columns per block
constexpr int GROUPS = 4;  // row groups (threadIdx.y)
constexpr int ROWS_PER = S_ / GROUPS; // 128

__global__ __launch_bounds__(CHUNK * GROUPS)
void aspire_segmean_kernel(const float* __restrict__ hidden,
                           const int* __restrict__ sent_ids,
                           float* __restrict__ out) {
    __shared__ float acc[M1 * CHUNK];   // 16128 B
    __shared__ int   sids[S_];          // 2048 B
    __shared__ int   cnt[M1];

    const int b   = blockIdx.x;
    const int dc  = blockIdx.y;          // which 192-col chunk
    const int c   = threadIdx.x;         // 0..191 (column within chunk)
    const int g   = threadIdx.y;         // 0..3   (row group)
    const int tid = g * CHUNK + c;       // 0..767

    // zero accumulators + counts
    for (int i = tid; i < M1 * CHUNK; i += CHUNK * GROUPS) acc[i] = 0.0f;
    if (tid < M1) cnt[tid] = 0;
    __syncthreads();

    // stage sent_ids + histogram counts
    if (tid < S_) {
        int sv = sent_ids[b * S_ + tid];
        sids[tid] = sv;
        atomicAdd(&cnt[sv], 1);
    }
    __syncthreads();

    // column base pointer: hidden[b][.][dc*CHUNK + c]
    const float* hp = hidden + (size_t)b * S_ * D_ + dc * CHUNK + c;

    // doc_cls_reps = hidden[:,0,:]
    if (g == 0) {
        out[b * D_ + dc * CHUNK + c] = hp[0];
    }

    // main accumulation: group g takes rows s = i*GROUPS + g
    #pragma unroll 16
    for (int i = 0; i < ROWS_PER; ++i) {
        int s = i * GROUPS + g;
        float v = hp[(size_t)s * D_];
        int sid = sids[s];                       // LDS broadcast read
        atomicAdd(&acc[sid * CHUNK + c], v);     // ds_add_f32, exclusive col -> conflict-free
    }
    __syncthreads();

    // epilogue: sent_reps[b][seg][dc*CHUNK + c] = acc / max(cnt,1)
    float* srep = out + (size_t)B_ * D_;
    for (int seg = g; seg < MS; seg += GROUPS) {
        float ct = (float)cnt[seg];
        ct = ct < 1.0f ? 1.0f : ct;
        srep[((size_t)b * MS + seg) * D_ + dc * CHUNK + c] =
            acc[seg * CHUNK + c] / ct;
    }
}

extern "C" void kernel_launch(void* const* d_in, const int* in_sizes, int n_in,
                              void* d_out, int out_size, void* d_ws, size_t ws_size,
                              hipStream_t stream) {
    const float* hidden   = (const float*)d_in[0];
    const int*   sent_ids = (const int*)d_in[1];
    // d_in[2] = max_sents scalar (compile-time constant 20 here)
    float* out = (float*)d_out;

    dim3 grid(B_, D_ / CHUNK);     // (64, 4) = 256 blocks
    dim3 block(CHUNK, GROUPS);     // (192, 4) = 768 threads = 12 waves
    aspire_segmean_kernel<<<grid, block, 0, stream>>>(hidden, sent_ids, out);
}